// Round 4
// baseline (2350.372 us; speedup 1.0000x reference)
//
#include <hip/hip_runtime.h>
#include <stdint.h>

#define BN_ 2
#define NPT 16384
#define MPT 8192
#define NROI 128
#define KP 2048
#define TFPS 512
#define WV 8

typedef unsigned long long u64;
typedef unsigned u32;

// ---- workspace layout (float offsets) ----
#define FEATS_LEN (4096*352)
#define CNTR_OFF  (FEATS_LEN)
#define CNTC_OFF  (CNTR_OFF + 4096)
#define FRAW_OFF  (CNTC_OFF + 4096)
#define FRAW_LEN  (BN_*NPT*32)
#define GC3_OFF   (FRAW_OFF + FRAW_LEN)
#define GC3_LEN   (BN_*MPT*64)
#define FLAGS_F_OFF (GC3_OFF + GC3_LEN)
#define CX_OFF    (FLAGS_F_OFF + (BN_*NPT)/4)
#define CY_OFF    (CX_OFF + BN_*NPT)
#define CZ_OFF    (CY_OFF + BN_*NPT)
#define SOID_OFF  (CZ_OFF + BN_*NPT)
#define OUT_KP_OFF (4096*128)

// ---------------- helpers ----------------
__device__ __forceinline__ u32 ordf(float f) {
    u32 b = __float_as_uint(f);
    return b ^ ((u32)(((int)b) >> 31) | 0x80000000u);
}
template <int CTRL>
__device__ __forceinline__ u32 dppmov(u32 v) {
    return (u32)__builtin_amdgcn_update_dpp((int)v, (int)v, CTRL, 0xF, 0xF, false);
}
__device__ __forceinline__ u64 wave_u64max(u64 k) {
    u32 lo = (u32)k, hi = (u32)(k >> 32);
#define STG(C) { u32 nl = dppmov<C>(lo), nh = dppmov<C>(hi); \
    bool g = (nh > hi) || (nh == hi && nl > lo); hi = g ? nh : hi; lo = g ? nl : lo; }
    STG(0x111) STG(0x112) STG(0x114) STG(0x118) STG(0x142) STG(0x143)
#undef STG
    hi = (u32)__builtin_amdgcn_readlane((int)hi, 63);
    lo = (u32)__builtin_amdgcn_readlane((int)lo, 63);
    return ((u64)hi << 32) | lo;
}
__device__ __forceinline__ float wave_fmin(float v) {
#define STG(C) { float o = __uint_as_float(dppmov<C>(__float_as_uint(v))); v = fminf(v, o); }
    STG(0x111) STG(0x112) STG(0x114) STG(0x118) STG(0x142) STG(0x143)
#undef STG
    return __uint_as_float((u32)__builtin_amdgcn_readlane((int)__float_as_uint(v), 63));
}
__device__ __forceinline__ float wave_fmax(float v) {
#define STG(C) { float o = __uint_as_float(dppmov<C>(__float_as_uint(v))); v = fmaxf(v, o); }
    STG(0x111) STG(0x112) STG(0x114) STG(0x118) STG(0x142) STG(0x143)
#undef STG
    return __uint_as_float((u32)__builtin_amdgcn_readlane((int)__float_as_uint(v), 63));
}
__device__ __forceinline__ u32 part4(u32 v) {
    v = (v | (v << 2)) & 0x33u; v = (v | (v << 1)) & 0x55u; return v;
}

// ---------------- K1: ROI validity flags (bit-exact vs reference) ----------------
__global__ void k_flags(const float* __restrict__ pts, const float* __restrict__ bbox,
                        unsigned char* __restrict__ flags) {
#pragma clang fp contract(off)
    __shared__ float rx[NROI], ry[NROI], rz[NROI], rt[NROI];
    int b = blockIdx.x >> 6;
    int t = threadIdx.x;
    if (t < NROI) {
        const float* rr = bbox + (size_t)(b * NROI + t) * 7;
        rx[t] = rr[0]; ry[t] = rr[1]; rz[t] = rr[2];
        float hx = rr[3] * 0.5f, hy = rr[4] * 0.5f, hz = rr[5] * 0.5f;
        rt[t] = sqrtf(((hx * hx) + (hy * hy)) + (hz * hz)) + 2.4f;
    }
    __syncthreads();
    int p = (blockIdx.x & 63) * 256 + t;
    const float* pr = pts + (size_t)(b * NPT + p) * 5;
    float x = pr[0], y = pr[1], z = pr[2];
    float mind = 3.4e38f, th = 0.f;
    for (int r = 0; r < NROI; ++r) {
        float dx = x - rx[r], dy = y - ry[r], dz = z - rz[r];
        float ds = sqrtf(((dx * dx) + (dy * dy)) + (dz * dz));
        if (ds < mind) { mind = ds; th = rt[r]; }
    }
    flags[b * NPT + p] = (mind < th) ? 1 : 0;
}

// ---------------- FPS core: register slots + wave-AABB exact pruning ----------------
template <int NS>
__device__ void fps_core(int t, int lane, int w, int V,
                         const float* __restrict__ SX, const float* __restrict__ SY,
                         const float* __restrict__ SZ, const int* __restrict__ SO,
                         u64 (*ck)[WV], float4 (*cxyz)[WV], float* __restrict__ kout) {
#pragma clang fp contract(off)
    float px[NS], py[NS], pz[NS], d[NS];
    u32 inv[NS];
    const int wbase = w * 64 * NS;
#pragma unroll
    for (int j = 0; j < NS; ++j) {
        int sid = wbase + j * 64 + lane;
        bool in = sid < V;
        px[j] = in ? SX[sid] : 3e38f;
        py[j] = in ? SY[sid] : 3e38f;
        pz[j] = in ? SZ[sid] : 3e38f;
        d[j]  = in ? 1e10f : -3.0e38f;
        inv[j] = in ? ~(u32)SO[sid] : ~(u32)(0x40000000u + (u32)sid);
    }
    // wave AABB over real slots
    float lx = 3e38f, ly = 3e38f, lz = 3e38f, hx = -3e38f, hy = -3e38f, hz = -3e38f;
#pragma unroll
    for (int j = 0; j < NS; ++j) {
        bool in = (wbase + j * 64 + lane) < V;
        lx = fminf(lx, px[j]); ly = fminf(ly, py[j]); lz = fminf(lz, pz[j]);
        hx = fmaxf(hx, in ? px[j] : -3e38f);
        hy = fmaxf(hy, in ? py[j] : -3e38f);
        hz = fmaxf(hz, in ? pz[j] : -3e38f);
    }
    lx = wave_fmin(lx); ly = wave_fmin(ly); lz = wave_fmin(lz);
    hx = wave_fmax(hx); hy = wave_fmax(hy); hz = wave_fmax(hz);

    // prime candidate
    u64 bestKey = 0; float bX = 0.f, bY = 0.f, bZ = 0.f;
#pragma unroll
    for (int j = 0; j < NS; ++j) {
        u64 kj = ((u64)ordf(d[j]) << 32) | inv[j];
        if (kj > bestKey) { bestKey = kj; bX = px[j]; bY = py[j]; bZ = pz[j]; }
    }
    {
        u64 wm = wave_u64max(bestKey);
        if (bestKey == wm) { ck[0][w] = wm; cxyz[0][w] = make_float4(bX, bY, bZ, 0.f); }
    }
    __syncthreads();

    for (int k = 0; k < KP; ++k) {
        int p = k & 1;
        // block winner: serial select over 8 wave candidates (uniform broadcast)
        u64 b0 = ck[p][0]; int bi = 0;
#pragma unroll
        for (int q = 1; q < WV; ++q) { u64 kq = ck[p][q]; if (kq > b0) { b0 = kq; bi = q; } }
        float4 wf = cxyz[p][bi];
        float bx = wf.x, by = wf.y, bz = wf.z;
        if (t == 0) { kout[k * 3] = bx; kout[k * 3 + 1] = by; kout[k * 3 + 2] = bz; }

        // exact skip test: dist2(winner, wave AABB) vs wave bestD (conservative margin)
        u64 ownK = ck[p][w];
        float bd = __uint_as_float(((u32)(ownK >> 32)) ^ 0x80000000u);
        float ddx = fmaxf(0.f, fmaxf(lx - bx, bx - hx));
        float ddy = fmaxf(0.f, fmaxf(ly - by, by - hy));
        float ddz = fmaxf(0.f, fmaxf(lz - bz, bz - hz));
        float ad2 = (ddx * ddx + ddy * ddy) + ddz * ddz;
        bool active = !(ad2 > bd * 1.00002f + 1e-6f);
        if (active) {
            bestKey = 0;
#pragma unroll
            for (int j = 0; j < NS; ++j) {
                float dx = px[j] - bx, dy = py[j] - by, dz = pz[j] - bz;
                float nd = ((dx * dx) + (dy * dy)) + dz * dz;
                float dn = fminf(d[j], nd);
                d[j] = dn;
                u64 kj = ((u64)ordf(dn) << 32) | inv[j];
                if (kj > bestKey) { bestKey = kj; bX = px[j]; bY = py[j]; bZ = pz[j]; }
            }
            u64 wm = wave_u64max(bestKey);
            if (bestKey == wm) { ck[p ^ 1][w] = wm; cxyz[p ^ 1][w] = make_float4(bX, bY, bZ, 0.f); }
        } else {
            if (lane == 0) { ck[p ^ 1][w] = ownK; cxyz[p ^ 1][w] = cxyz[p][w]; }
        }
        __syncthreads();
    }
}

// ---------------- K2: Morton counting-sort of valid points + pruned exact FPS ----------------
__global__ void __launch_bounds__(TFPS, 1)
k_fps(const float* __restrict__ pts, const unsigned char* __restrict__ flags,
      float* __restrict__ sxg, float* __restrict__ syg, float* __restrict__ szg,
      int* __restrict__ soidg, float* __restrict__ kpOut) {
#pragma clang fp contract(off)
    __shared__ int hist[256];
    __shared__ int wsum[WV];
    __shared__ u64 ck[2][WV];
    __shared__ float4 cxyz[2][WV];

    int b = blockIdx.x, t = threadIdx.x, lane = t & 63, w = t >> 6;
    const float* pbase = pts + (size_t)b * NPT * 5;
    const unsigned char* fb = flags + b * NPT;
    float* SX = sxg + (size_t)b * NPT;
    float* SY = syg + (size_t)b * NPT;
    float* SZ = szg + (size_t)b * NPT;
    int*   SO = soidg + (size_t)b * NPT;

    for (int i = t; i < 256; i += TFPS) hist[i] = 0;
    __syncthreads();

    // pass 1: flags, cells, histogram
    int chunk = t * 32;
    u32 fl = 0, cells[8];
#pragma unroll
    for (int i = 0; i < 8; ++i) cells[i] = 0;
    int cnt = 0;
    for (int j = 0; j < 32; ++j) {
        if (fb[chunk + j]) {
            const float* pr = pbase + (size_t)(chunk + j) * 5;
            float x = pr[0], y = pr[1];
            int cxi = (int)fmaxf(0.f, fminf(15.f, (x + 75.2f) * (16.0f / 150.4f)));
            int cyi = (int)fmaxf(0.f, fminf(15.f, (y + 75.2f) * (16.0f / 150.4f)));
            u32 cell = part4((u32)cxi) | (part4((u32)cyi) << 1);
            atomicAdd(&hist[cell], 1);
            cells[j >> 2] |= cell << ((j & 3) * 8);
            fl |= 1u << j;
            ++cnt;
        }
    }
    // V = block total
    int s = cnt;
#pragma unroll
    for (int m = 1; m < 64; m <<= 1) s += __shfl_xor(s, m, 64);
    if (lane == 0) wsum[w] = s;
    __syncthreads();
    int V = 0;
    for (int i = 0; i < WV; ++i) V += wsum[i];
    __syncthreads();

    // exclusive scan of 256 bins
    int v = (t < 256) ? hist[t] : 0;
    int incl = v;
#pragma unroll
    for (int off = 1; off < 64; off <<= 1) {
        int u = __shfl_up(incl, off, 64);
        if (lane >= off) incl += u;
    }
    if (lane == 63) wsum[w] = incl;
    __syncthreads();
    if (t < 256) {
        int off = 0;
        for (int i = 0; i < w; ++i) off += wsum[i];
        hist[t] = off + incl - v;   // exclusive start; reused as cursor
    }
    __syncthreads();

    // pass 2: scatter to sorted SoA (cursor atomics; order within cell irrelevant)
    for (int j = 0; j < 32; ++j) {
        if ((fl >> j) & 1u) {
            u32 cell = (cells[j >> 2] >> ((j & 3) * 8)) & 0xFFu;
            int pos = atomicAdd(&hist[cell], 1);
            const float* pr = pbase + (size_t)(chunk + j) * 5;
            SX[pos] = pr[0]; SY[pos] = pr[1]; SZ[pos] = pr[2];
            SO[pos] = chunk + j;
        }
    }
    __syncthreads();

    float* kout = kpOut + (size_t)b * KP * 3;
    if (V == 0) {   // degenerate: reference picks index 0 every step
        if (t == 0)
            for (int k = 0; k < KP; ++k) {
                kout[k * 3] = pbase[0]; kout[k * 3 + 1] = pbase[1]; kout[k * 3 + 2] = pbase[2];
            }
        return;
    }
    int nsw = (V + TFPS - 1) / TFPS;
    if (nsw <= 10)      fps_core<10>(t, lane, w, V, SX, SY, SZ, SO, ck, cxyz, kout);
    else if (nsw <= 12) fps_core<12>(t, lane, w, V, SX, SY, SZ, SO, ck, cxyz, kout);
    else if (nsw <= 16) fps_core<16>(t, lane, w, V, SX, SY, SZ, SO, ck, cxyz, kout);
    else if (nsw <= 24) fps_core<24>(t, lane, w, V, SX, SY, SZ, SO, ck, cxyz, kout);
    else                fps_core<32>(t, lane, w, V, SX, SY, SZ, SO, ck, cxyz, kout);
}

// ---------------- K3: bilinear BEV sampling ----------------
__global__ void k_bilinear(const float* __restrict__ sf, const float* __restrict__ kp,
                           float* __restrict__ feats) {
    int bid = blockIdx.x;
    int b = bid >> 11, kk = bid & 2047;
    int c = threadIdx.x;
    const float* kpr = kp + (size_t)(b * KP + kk) * 3;
    float x = kpr[0], y = kpr[1];
    float xi = ((x - (-75.2f)) / 0.1f) / 8.0f;
    float yi = ((y - (-75.2f)) / 0.1f) / 8.0f;
    int x0 = (int)floorf(xi); x0 = min(max(x0, 0), 187);
    int x1 = min(max(x0 + 1, 0), 187);
    int y0 = (int)floorf(yi); y0 = min(max(y0, 0), 187);
    int y1 = min(max(y0 + 1, 0), 187);
    float xf0 = (float)x0, xf1 = (float)x1, yf0 = (float)y0, yf1 = (float)y1;
    float wa = (xf1 - xi) * (yf1 - yi), wb = (xf1 - xi) * (yi - yf0);
    float wc = (xi - xf0) * (yf1 - yi), wd = (xi - xf0) * (yi - yf0);
    const float* plane = sf + (size_t)(b * 256 + c) * 188 * 188;
    float Ia = plane[y0 * 188 + x0], Ib = plane[y1 * 188 + x0];
    float Ic = plane[y0 * 188 + x1], Id = plane[y1 * 188 + x1];
    feats[(size_t)(b * KP + kk) * 352 + c] = Ia * wa + Ib * wb + Ic * wc + Id * wd;
}

// ---------------- K4a: raw point feature MLP ----------------
__global__ void k_fraw(const float* __restrict__ pts, const float* __restrict__ Wr,
                       const float* __restrict__ br, float* __restrict__ fraw) {
    int idx = blockIdx.x * 256 + threadIdx.x;
    int c = idx & 31, n = idx >> 5;
    const float* pr = pts + (size_t)n * 5;
    float v = pr[3] * Wr[c] + pr[4] * Wr[32 + c] + br[c];
    fraw[(size_t)n * 32 + c] = fmaxf(v, 0.f);
}

// ---------------- K4b: conv3 point feature MLP ----------------
__global__ void k_gc3(const float* __restrict__ conv3, const float* __restrict__ Wc,
                      const float* __restrict__ bc, float* __restrict__ gc3) {
    __shared__ float w[4096];
    __shared__ float rf[4][64];
    int t = threadIdx.x;
    for (int i = t; i < 4096; i += 256) w[i] = Wc[i];
    int r = blockIdx.x * 4 + (t >> 6);
    int c = t & 63;
    rf[t >> 6][c] = conv3[(size_t)r * 67 + 3 + c];
    __syncthreads();
    float s = bc[c];
#pragma unroll 8
    for (int k = 0; k < 64; ++k) s = fmaf(rf[t >> 6][k], w[k * 64 + c], s);
    gc3[(size_t)r * 64 + c] = fmaxf(s, 0.f);
}

// ---------------- K5: raw radius aggregation ----------------
__global__ void k_rawagg(const float* __restrict__ pts, const float* __restrict__ kp,
                         const float* __restrict__ fraw, float* __restrict__ feats,
                         float* __restrict__ cntR) {
    __shared__ float sp[2560];
    int bid = blockIdx.x;
    int b = bid >> 7, kb = (bid >> 4) & 7, s = bid & 15;
    int t = threadIdx.x;
    int kk = kb * 256 + t, row = b * KP + kk;
    float kx = kp[row * 3], ky = kp[row * 3 + 1], kz = kp[row * 3 + 2];
    float acc[32];
#pragma unroll
    for (int c = 0; c < 32; ++c) acc[c] = 0.f;
    float cnt = 0.f;
    const float R2 = 0.8f * 0.8f;
    for (int tile = 0; tile < 2; ++tile) {
        int nbase = s * 1024 + tile * 512;
        const float* src = pts + (size_t)(b * NPT + nbase) * 5;
        for (int i = t; i < 2560; i += 256) sp[i] = src[i];
        __syncthreads();
        for (int j = 0; j < 512; ++j) {
            float dx = kx - sp[j * 5], dy = ky - sp[j * 5 + 1], dz = kz - sp[j * 5 + 2];
            float d2 = fmaf(dx, dx, fmaf(dy, dy, dz * dz));
            if (d2 < R2) {
                cnt += 1.f;
                const float* fp = fraw + (size_t)(b * NPT + nbase + j) * 32;
#pragma unroll
                for (int c = 0; c < 32; ++c) acc[c] += fp[c];
            }
        }
        __syncthreads();
    }
    float* dst = feats + (size_t)row * 352 + 256;
#pragma unroll
    for (int c = 0; c < 32; ++c) if (acc[c] != 0.f) atomicAdd(dst + c, acc[c]);
    if (cnt != 0.f) atomicAdd(cntR + row, cnt);
}

// ---------------- K6: conv3 radius aggregation ----------------
__global__ void k_c3agg(const float* __restrict__ conv3, const float* __restrict__ kp,
                        const float* __restrict__ gc3, float* __restrict__ feats,
                        float* __restrict__ cntC) {
    __shared__ float sq[256 * 3];
    int bid = blockIdx.x;
    int b = bid >> 7, kb = (bid >> 4) & 7, s = bid & 15;
    int t = threadIdx.x;
    int kk = kb * 256 + t, row = b * KP + kk;
    float kx = kp[row * 3], ky = kp[row * 3 + 1], kz = kp[row * 3 + 2];
    float acc[64];
#pragma unroll
    for (int c = 0; c < 64; ++c) acc[c] = 0.f;
    float cnt = 0.f;
    const float R2 = 1.6f * 1.6f;
    for (int tile = 0; tile < 2; ++tile) {
        int nbase = s * 512 + tile * 256;
        const float* src = conv3 + (size_t)(b * MPT + nbase + t) * 67;
        sq[t * 3] = src[0]; sq[t * 3 + 1] = src[1]; sq[t * 3 + 2] = src[2];
        __syncthreads();
        for (int j = 0; j < 256; ++j) {
            float dx = kx - sq[j * 3], dy = ky - sq[j * 3 + 1], dz = kz - sq[j * 3 + 2];
            float d2 = fmaf(dx, dx, fmaf(dy, dy, dz * dz));
            if (d2 < R2) {
                cnt += 1.f;
                const float* gp = gc3 + (size_t)(b * MPT + nbase + j) * 64;
#pragma unroll
                for (int c = 0; c < 64; ++c) acc[c] += gp[c];
            }
        }
        __syncthreads();
    }
    float* dst = feats + (size_t)row * 352 + 288;
#pragma unroll
    for (int c = 0; c < 64; ++c) if (acc[c] != 0.f) atomicAdd(dst + c, acc[c]);
    if (cnt != 0.f) atomicAdd(cntC + row, cnt);
}

// ---------------- K7: fuse GEMM + BN + ReLU ----------------
__global__ void k_fuse(const float* __restrict__ feats, const float* __restrict__ cntR,
                       const float* __restrict__ cntC, const float* __restrict__ Wf,
                       const float* __restrict__ gma, const float* __restrict__ bta,
                       const float* __restrict__ mean, const float* __restrict__ var,
                       float* __restrict__ out) {
    __shared__ float a[2][352];
    int r0 = blockIdx.x * 2;
    int t = threadIdx.x;
    for (int i = t; i < 704; i += 256) {
        int rr = i >= 352 ? 1 : 0;
        int k = i - rr * 352;
        float v = feats[(size_t)(r0 + rr) * 352 + k];
        if (k >= 256) {
            float cn = (k < 288) ? cntR[r0 + rr] : cntC[r0 + rr];
            v = v / fmaxf(cn, 1.0f);
        }
        a[rr][k] = v;
    }
    __syncthreads();
    int r = t >> 7, c = t & 127;
    float s = 0.f;
#pragma unroll 4
    for (int k = 0; k < 352; ++k) s = fmaf(a[r][k], Wf[k * 128 + c], s);
    s = (s - mean[c]) * (1.0f / sqrtf(var[c] + 1e-5f)) * gma[c] + bta[c];
    out[(size_t)(r0 + r) * 128 + c] = fmaxf(s, 0.f);
}

// ---------------- launch ----------------
extern "C" void kernel_launch(void* const* d_in, const int* in_sizes, int n_in,
                              void* d_out, int out_size, void* d_ws, size_t ws_size,
                              hipStream_t stream) {
    const float* pts   = (const float*)d_in[0];
    const float* bbox  = (const float*)d_in[1];
    const float* sf    = (const float*)d_in[2];
    const float* conv3 = (const float*)d_in[3];
    const float* Wraw  = (const float*)d_in[4];
    const float* braw  = (const float*)d_in[5];
    const float* Wc3   = (const float*)d_in[6];
    const float* bc3   = (const float*)d_in[7];
    const float* Wf    = (const float*)d_in[8];
    const float* gma   = (const float*)d_in[9];
    const float* bta   = (const float*)d_in[10];
    const float* mean  = (const float*)d_in[11];
    const float* var   = (const float*)d_in[12];

    float* wsf   = (float*)d_ws;
    float* feats = wsf;
    float* cntR  = wsf + CNTR_OFF;
    float* cntC  = wsf + CNTC_OFF;
    float* fraw  = wsf + FRAW_OFF;
    float* gc3   = wsf + GC3_OFF;
    unsigned char* flags = (unsigned char*)(wsf + FLAGS_F_OFF);
    float* sxg   = wsf + CX_OFF;
    float* syg   = wsf + CY_OFF;
    float* szg   = wsf + CZ_OFF;
    int*   soidg = (int*)(wsf + SOID_OFF);

    float* outp  = (float*)d_out;
    float* kpOut = outp + OUT_KP_OFF;

    hipMemsetAsync(d_ws, 0, (size_t)(FEATS_LEN + 8192) * 4, stream);

    k_flags<<<BN_ * 64, 256, 0, stream>>>(pts, bbox, flags);
    k_fps<<<BN_, TFPS, 0, stream>>>(pts, flags, sxg, syg, szg, soidg, kpOut);
    k_bilinear<<<BN_ * KP, 256, 0, stream>>>(sf, kpOut, feats);
    k_fraw<<<(BN_ * NPT * 32) / 256, 256, 0, stream>>>(pts, Wraw, braw, fraw);
    k_gc3<<<(BN_ * MPT) / 4, 256, 0, stream>>>(conv3, Wc3, bc3, gc3);
    k_rawagg<<<BN_ * 128, 256, 0, stream>>>(pts, kpOut, fraw, feats, cntR);
    k_c3agg<<<BN_ * 128, 256, 0, stream>>>(conv3, kpOut, gc3, feats, cntC);
    k_fuse<<<2048, 256, 0, stream>>>(feats, cntR, cntC, Wf, gma, bta, mean, var, outp);
}